// Round 1
// baseline (313.916 us; speedup 1.0000x reference)
//
#include <hip/hip_runtime.h>

// ---------- types ----------
typedef _Float16 f16x8 __attribute__((ext_vector_type(8)));
typedef _Float16 f16x4 __attribute__((ext_vector_type(4)));
typedef float    f32x4 __attribute__((ext_vector_type(4)));
typedef unsigned short ushort_t;

#define LOG2E 1.44269504088896340736f

__device__ __forceinline__ ushort_t f2h(float x) {
  _Float16 h = (_Float16)x;
  return __builtin_bit_cast(ushort_t, h);
}

// async global->LDS, 16B per lane. LDS dest must be wave-uniform base;
// HW adds lane*16. Generic->AS3 via low-32-bit truncation (LLVM's
// flat->local lowering), generic->AS1 is identity.
__device__ __forceinline__ void gload_lds16(const void* g, void* lds) {
  __builtin_amdgcn_global_load_lds(
      (const __attribute__((address_space(1))) void*)(uintptr_t)g,
      (__attribute__((address_space(3))) void*)(unsigned)(uintptr_t)lds,
      16, 0, 0);
}

// ---------- LocalRmsNorm: pass A (horizontal 7-tap box of x^2) ----------
// x: [8][1024][768] f32 ; tmp same shape f32
__global__ __launch_bounds__(256)
void lrn_a(const float* __restrict__ x, float* __restrict__ tmp) {
  int tid = blockIdx.x * 256 + threadIdx.x;     // 8*1024*192 threads
  int dv  = tid % 192;
  int rem = tid / 192;
  int pos = rem & 1023;
  int b   = rem >> 10;
  int r = pos >> 5, c = pos & 31;
  const float4* base = (const float4*)x + ((size_t)b * 1024 + (size_t)r * 32) * 192 + dv;
  float ax = 0.f, ay = 0.f, az = 0.f, aw = 0.f;
#pragma unroll
  for (int dc = -3; dc <= 3; ++dc) {
    int cc = c + dc;
    if (cc >= 0 && cc < 32) {
      float4 v = base[cc * 192];
      ax += v.x * v.x; ay += v.y * v.y; az += v.z * v.z; aw += v.w * v.w;
    }
  }
  float4 o; o.x = ax; o.y = ay; o.z = az; o.w = aw;
  ((float4*)tmp)[tid] = o;
}

// ---------- LocalRmsNorm: pass B (vertical 7-tap) -> xn (f16) ----------
__global__ __launch_bounds__(256)
void lrn_b(const float* __restrict__ x, const float* __restrict__ tmp,
           const float* __restrict__ wn, ushort_t* __restrict__ xn) {
  int tid = blockIdx.x * 256 + threadIdx.x;
  int dv  = tid % 192;
  int rem = tid / 192;
  int pos = rem & 1023;
  int b   = rem >> 10;
  int r = pos >> 5, c = pos & 31;
  const float4* tb = (const float4*)tmp + ((size_t)b * 1024 + c) * 192 + dv;
  float ax = 0.f, ay = 0.f, az = 0.f, aw = 0.f;
#pragma unroll
  for (int dr = -3; dr <= 3; ++dr) {
    int rr = r + dr;
    if (rr >= 0 && rr < 32) {
      float4 v = tb[(size_t)rr * 32 * 192];
      ax += v.x; ay += v.y; az += v.z; aw += v.w;
    }
  }
  float4 xv = ((const float4*)x)[tid];
  float4 wv = ((const float4*)wn)[dv];
  const float inv49 = 1.0f / 49.0f;
  float i0 = 1.0f / sqrtf(1e-7f + ax * inv49);
  float i1 = 1.0f / sqrtf(1e-7f + ay * inv49);
  float i2 = 1.0f / sqrtf(1e-7f + az * inv49);
  float i3 = 1.0f / sqrtf(1e-7f + aw * inv49);
  f16x4 o;
  o[0] = (_Float16)(xv.x * i0 * wv.x);
  o[1] = (_Float16)(xv.y * i1 * wv.y);
  o[2] = (_Float16)(xv.z * i2 * wv.z);
  o[3] = (_Float16)(xv.w * i3 * wv.w);
  *(f16x4*)(xn + (size_t)tid * 4) = o;
}

// ---------- weight conversion f32 -> f16 ----------
// bqkv: [2304][768] = concat(wq, wk, wv) rows ; bwo: [768][768]
__global__ __launch_bounds__(256)
void convw(const float* __restrict__ wq, const float* __restrict__ wk,
           const float* __restrict__ wv, const float* __restrict__ wo,
           ushort_t* __restrict__ bqkv, ushort_t* __restrict__ bwo) {
  int tid = blockIdx.x * 256 + threadIdx.x;   // 589824/4 threads
  float4 a = ((const float4*)wq)[tid];
  float4 b = ((const float4*)wk)[tid];
  float4 c = ((const float4*)wv)[tid];
  float4 d = ((const float4*)wo)[tid];
  f16x4 pa, pb, pc, pd;
  pa[0]=(_Float16)a.x; pa[1]=(_Float16)a.y; pa[2]=(_Float16)a.z; pa[3]=(_Float16)a.w;
  pb[0]=(_Float16)b.x; pb[1]=(_Float16)b.y; pb[2]=(_Float16)b.z; pb[3]=(_Float16)b.w;
  pc[0]=(_Float16)c.x; pc[1]=(_Float16)c.y; pc[2]=(_Float16)c.z; pc[3]=(_Float16)c.w;
  pd[0]=(_Float16)d.x; pd[1]=(_Float16)d.y; pd[2]=(_Float16)d.z; pd[3]=(_Float16)d.w;
  ((f16x4*)bqkv)[tid]             = pa;
  ((f16x4*)(bqkv + 589824))[tid]  = pb;
  ((f16x4*)(bqkv + 1179648))[tid] = pc;
  ((f16x4*)bwo)[tid]              = pd;
}

// ---------- GEMM: out[m][n] = sum_k A[m][k]*B[n][k] (+bias) ----------
// A: [8192][768] f16, B: [N][768] f16 (row-major, K-contiguous, i.e. B^T input)
// MODE 0: N=2304 -> scatter Q (scaled 0.125), K, V^T (f16)
// MODE 1: N=768  -> d_out fp32 row-major
template <int MODE>
__global__ __launch_bounds__(256)
void gemm_f16(const ushort_t* __restrict__ A, const ushort_t* __restrict__ B,
              const float* __restrict__ b0, const float* __restrict__ b1,
              const float* __restrict__ b2,
              ushort_t* __restrict__ q, ushort_t* __restrict__ k,
              ushort_t* __restrict__ v, float* __restrict__ outf, int nbn) {
  __shared__ __align__(16) ushort_t As[128 * 32];
  __shared__ __align__(16) ushort_t Bs[128 * 32];

  const int bid = blockIdx.x;
  const int bm = bid / nbn, bn = bid % nbn;
  const int tid = threadIdx.x;
  const int w = tid >> 6, l = tid & 63;
  const int wr = w >> 1, wc = w & 1;
  const int lr = l & 15, lg = l >> 4;

  f32x4 acc[4][4] = {};

  const ushort_t* Ab = A + (size_t)bm * 128 * 768;
  const ushort_t* Bb = B + (size_t)bn * 128 * 768;
  const int srow = w * 32 + (l >> 2);
  const int scol = (l & 3) * 8;

  for (int kt = 0; kt < 24; ++kt) {
    const int k0 = kt * 32;
    gload_lds16(Ab + (size_t)srow * 768 + k0 + scol,        As + (w * 32) * 32);
    gload_lds16(Ab + (size_t)(srow + 16) * 768 + k0 + scol, As + (w * 32 + 16) * 32);
    gload_lds16(Bb + (size_t)srow * 768 + k0 + scol,        Bs + (w * 32) * 32);
    gload_lds16(Bb + (size_t)(srow + 16) * 768 + k0 + scol, Bs + (w * 32 + 16) * 32);
    __syncthreads();
    f16x8 af[4], bf[4];
#pragma unroll
    for (int r = 0; r < 4; ++r)
      af[r] = *(const f16x8*)(As + (wr * 64 + r * 16 + lr) * 32 + lg * 8);
#pragma unroll
    for (int c = 0; c < 4; ++c)
      bf[c] = *(const f16x8*)(Bs + (wc * 64 + c * 16 + lr) * 32 + lg * 8);
#pragma unroll
    for (int r = 0; r < 4; ++r)
#pragma unroll
      for (int c = 0; c < 4; ++c)
        acc[r][c] = __builtin_amdgcn_mfma_f32_16x16x32_f16(af[r], bf[c], acc[r][c], 0, 0, 0);
    __syncthreads();
  }

  // epilogue. C/D layout: col = lane&15, row = (lane>>4)*4 + reg  [m89/m91]
#pragma unroll
  for (int r = 0; r < 4; ++r) {
#pragma unroll
    for (int c = 0; c < 4; ++c) {
      const int n = bn * 128 + wc * 64 + c * 16 + lr;
      const int mbase = bm * 128 + wr * 64 + r * 16 + lg * 4;
      if (MODE == 0) {
        const int region = n / 768;          // uniform per block (768%128==0)
        const int nn = n - region * 768;
        const int hh = nn >> 6, hd = nn & 63;
        const float bb = (region == 0 ? b0 : region == 1 ? b1 : b2)[nn];
        if (region == 2) {
          // V^T: 4 regs -> 4 consecutive s -> one 8B store
          const int bi = mbase >> 10, s0 = mbase & 1023;
          f16x4 pv;
#pragma unroll
          for (int g = 0; g < 4; ++g) pv[g] = (_Float16)(acc[r][c][g] + bb);
          *(f16x4*)(v + (((size_t)(bi * 12 + hh)) * 64 + hd) * 1024 + s0) = pv;
        } else {
#pragma unroll
          for (int g = 0; g < 4; ++g) {
            const int m = mbase + g;
            const int bi = m >> 10, s = m & 1023;
            const float val = acc[r][c][g] + bb;
            if (region == 0)
              q[(((size_t)(bi * 12 + hh)) * 1024 + s) * 64 + hd] = f2h(val * 0.125f);
            else
              k[(((size_t)(bi * 12 + hh)) * 1024 + s) * 64 + hd] = f2h(val);
          }
        }
      } else {
        const float bb = b0[n];
#pragma unroll
        for (int g = 0; g < 4; ++g) {
          const int m = mbase + g;
          outf[(size_t)m * 768 + n] = acc[r][c][g] + bb;
        }
      }
    }
  }
}

// ---------- fused flash attention ----------
// qb/kb: [96][1024][64] f16 (q pre-scaled by 0.125), vt: [96][64][1024] f16
// ao: [8192][768] f16
__global__ __launch_bounds__(256)
void attn_fused(const ushort_t* __restrict__ qb, const ushort_t* __restrict__ kb,
                const ushort_t* __restrict__ vt, ushort_t* __restrict__ ao) {
  __shared__ __align__(16) ushort_t P[4][16][72];
  const int tid = threadIdx.x;
  const int w = tid >> 6, l = tid & 63;
  const int lr = l & 15, lg = l >> 4;
  const int bh = blockIdx.x % 96;   // blocks sharing K/V land on same XCD
  const int qt = blockIdx.x / 96;
  const int b = bh / 12, h = bh % 12;
  const int q0 = qt * 64 + w * 16;

  const ushort_t* qp = qb + ((size_t)bh * 1024 + q0) * 64;
  const ushort_t* kp = kb + (size_t)bh * 65536;
  const ushort_t* vp = vt + (size_t)bh * 65536;

  // Q A-frags (row = lane&15, k = (lane>>4)*8 + i), k-chunks 0..31 / 32..63
  const f16x8 aq0 = *(const f16x8*)(qp + lr * 64 + lg * 8);
  const f16x8 aq1 = *(const f16x8*)(qp + lr * 64 + 32 + lg * 8);

  f32x4 oacc[4] = {};
  float mrun[4] = {-1e30f, -1e30f, -1e30f, -1e30f};
  float lrun[4] = {0.f, 0.f, 0.f, 0.f};

  for (int t = 0; t < 16; ++t) {
    const int kv0 = t * 64;
    f32x4 sacc[4] = {};
    // S = (Q/8) K^T : B-frag lane holds K[kv=ct*16+(l&15)][k-chunk], contiguous
#pragma unroll
    for (int ct = 0; ct < 4; ++ct) {
      const ushort_t* kr = kp + (size_t)(kv0 + ct * 16 + lr) * 64 + lg * 8;
      f16x8 bk0 = *(const f16x8*)kr;
      f16x8 bk1 = *(const f16x8*)(kr + 32);
      sacc[ct] = __builtin_amdgcn_mfma_f32_16x16x32_f16(aq0, bk0, sacc[ct], 0, 0, 0);
      sacc[ct] = __builtin_amdgcn_mfma_f32_16x16x32_f16(aq1, bk1, sacc[ct], 0, 0, 0);
    }
    // online softmax: row g lives on the 16 lanes sharing lg; reduce via xor 1,2,4,8
#pragma unroll
    for (int g = 0; g < 4; ++g) {
      float mx = fmaxf(fmaxf(sacc[0][g], sacc[1][g]), fmaxf(sacc[2][g], sacc[3][g]));
      mx = fmaxf(mx, __shfl_xor(mx, 1, 64));
      mx = fmaxf(mx, __shfl_xor(mx, 2, 64));
      mx = fmaxf(mx, __shfl_xor(mx, 4, 64));
      mx = fmaxf(mx, __shfl_xor(mx, 8, 64));
      const float mnew = fmaxf(mrun[g], mx);
      const float corr = __builtin_exp2f((mrun[g] - mnew) * LOG2E);
      mrun[g] = mnew;
      float sum = 0.f;
#pragma unroll
      for (int ct = 0; ct < 4; ++ct) {
        float p = __builtin_exp2f((sacc[ct][g] - mnew) * LOG2E);
        sacc[ct][g] = p;
        sum += p;
      }
      sum += __shfl_xor(sum, 1, 64);
      sum += __shfl_xor(sum, 2, 64);
      sum += __shfl_xor(sum, 4, 64);
      sum += __shfl_xor(sum, 8, 64);
      lrun[g] = lrun[g] * corr + sum;
#pragma unroll
      for (int ct = 0; ct < 4; ++ct) oacc[ct][g] *= corr;
    }
    // P -> LDS (transpose to A-frag layout), wave-private tile
#pragma unroll
    for (int ct = 0; ct < 4; ++ct)
#pragma unroll
      for (int g = 0; g < 4; ++g)
        P[w][lg * 4 + g][ct * 16 + lr] = f2h(sacc[ct][g]);
    const f16x8 pa0 = *(const f16x8*)(&P[w][lr][lg * 8]);
    const f16x8 pa1 = *(const f16x8*)(&P[w][lr][32 + lg * 8]);
    // O += P V : B-frag from V^T rows (contiguous kv)
#pragma unroll
    for (int ct = 0; ct < 4; ++ct) {
      const ushort_t* vr = vp + (size_t)(ct * 16 + lr) * 1024 + kv0 + lg * 8;
      f16x8 v0 = *(const f16x8*)vr;
      f16x8 v1 = *(const f16x8*)(vr + 32);
      oacc[ct] = __builtin_amdgcn_mfma_f32_16x16x32_f16(pa0, v0, oacc[ct], 0, 0, 0);
      oacc[ct] = __builtin_amdgcn_mfma_f32_16x16x32_f16(pa1, v1, oacc[ct], 0, 0, 0);
    }
  }
  // finalize + write [b][s][h*64+hd] f16
#pragma unroll
  for (int ct = 0; ct < 4; ++ct)
#pragma unroll
    for (int g = 0; g < 4; ++g) {
      const float val = oacc[ct][g] / lrun[g];
      const int qrow = q0 + lg * 4 + g;
      ao[((size_t)(b * 1024 + qrow)) * 768 + h * 64 + ct * 16 + lr] = f2h(val);
    }
}

// ---------- launch ----------
extern "C" void kernel_launch(void* const* d_in, const int* in_sizes, int n_in,
                              void* d_out, int out_size, void* d_ws, size_t ws_size,
                              hipStream_t stream) {
  const float* x  = (const float*)d_in[0];
  const float* nw = (const float*)d_in[1];
  const float* wq = (const float*)d_in[2];
  const float* bq = (const float*)d_in[3];
  const float* wk = (const float*)d_in[4];
  const float* bk = (const float*)d_in[5];
  const float* wv = (const float*)d_in[6];
  const float* bv = (const float*)d_in[7];
  const float* wo = (const float*)d_in[8];
  const float* bo = (const float*)d_in[9];
  float* out = (float*)d_out;

  char* ws = (char*)d_ws;
  // tmp (25,165,824 B fp32) is consumed by lrn_b, then its region is reused
  // for qbuf+kbuf (12,582,912 B each) written later by gemm_f16<0>.
  float*    tmp   = (float*)ws;
  ushort_t* qbuf  = (ushort_t*)(ws);
  ushort_t* kbuf  = (ushort_t*)(ws + 12582912);
  ushort_t* xn    = (ushort_t*)(ws + 25165824);   // 12,582,912
  ushort_t* bwqkv = (ushort_t*)(ws + 37748736);   //  3,538,944
  ushort_t* bwo   = (ushort_t*)(ws + 41287680);   //  1,179,648
  ushort_t* vtb   = (ushort_t*)(ws + 42467328);   // 12,582,912
  ushort_t* aout  = (ushort_t*)(ws + 55050240);   // 12,582,912  (total 67,633,152)

  lrn_a<<<6144, 256, 0, stream>>>(x, tmp);
  lrn_b<<<6144, 256, 0, stream>>>(x, tmp, nw, xn);
  convw<<<576, 256, 0, stream>>>(wq, wk, wv, wo, bwqkv, bwo);
  gemm_f16<0><<<64 * 18, 256, 0, stream>>>(xn, bwqkv, bq, bk, bv,
                                           qbuf, kbuf, vtb, nullptr, 18);
  attn_fused<<<1536, 256, 0, stream>>>(qbuf, kbuf, vtb, aout);
  gemm_f16<1><<<64 * 6, 256, 0, stream>>>(aout, bwo, bo, nullptr, nullptr, nullptr,
                                          nullptr, nullptr, out, 6);
}

// Round 2
// 175.228 us; speedup vs baseline: 1.7915x; 1.7915x over previous
//
#include <hip/hip_runtime.h>

// ---------- types ----------
typedef _Float16 f16x8 __attribute__((ext_vector_type(8)));
typedef _Float16 f16x4 __attribute__((ext_vector_type(4)));
typedef _Float16 f16x2 __attribute__((ext_vector_type(2)));
typedef float    f32x4 __attribute__((ext_vector_type(4)));
typedef float    f32x16 __attribute__((ext_vector_type(16)));
typedef unsigned int u32x4 __attribute__((ext_vector_type(4)));
typedef unsigned short ushort_t;
typedef unsigned int uint_t;

#define LOG2E 1.44269504088896340736f

__device__ __forceinline__ ushort_t f2h(float x) {
  _Float16 h = (_Float16)x;
  return __builtin_bit_cast(ushort_t, h);
}

__device__ __forceinline__ uint_t packpair(float a, float b) {
  f16x2 p; p[0] = (_Float16)a; p[1] = (_Float16)b;
  return __builtin_bit_cast(uint_t, p);
}

__device__ __forceinline__ f16x8 mk8(uint_t a, uint_t b, uint_t c, uint_t d) {
  u32x4 t; t[0] = a; t[1] = b; t[2] = c; t[3] = d;
  return __builtin_bit_cast(f16x8, t);
}

// async global->LDS, 16B per lane. LDS dest is wave-uniform base + lane*16.
__device__ __forceinline__ void gload_lds16(const void* g, void* lds) {
  __builtin_amdgcn_global_load_lds(
      (const __attribute__((address_space(1))) void*)(uintptr_t)g,
      (__attribute__((address_space(3))) void*)(unsigned)(uintptr_t)lds,
      16, 0, 0);
}

// ---------- LocalRmsNorm: pass A (horizontal 7-tap box of x^2) ----------
__global__ __launch_bounds__(256)
void lrn_a(const float* __restrict__ x, float* __restrict__ tmp) {
  int tid = blockIdx.x * 256 + threadIdx.x;     // 8*1024*192 threads
  int dv  = tid % 192;
  int rem = tid / 192;
  int pos = rem & 1023;
  int b   = rem >> 10;
  int r = pos >> 5, c = pos & 31;
  const float4* base = (const float4*)x + ((size_t)b * 1024 + (size_t)r * 32) * 192 + dv;
  float ax = 0.f, ay = 0.f, az = 0.f, aw = 0.f;
#pragma unroll
  for (int dc = -3; dc <= 3; ++dc) {
    int cc = c + dc;
    if (cc >= 0 && cc < 32) {
      float4 v = base[cc * 192];
      ax += v.x * v.x; ay += v.y * v.y; az += v.z * v.z; aw += v.w * v.w;
    }
  }
  float4 o; o.x = ax; o.y = ay; o.z = az; o.w = aw;
  ((float4*)tmp)[tid] = o;
}

// ---------- LocalRmsNorm: pass B (vertical 7-tap) -> xn (f16) ----------
__global__ __launch_bounds__(256)
void lrn_b(const float* __restrict__ x, const float* __restrict__ tmp,
           const float* __restrict__ wn, ushort_t* __restrict__ xn) {
  int tid = blockIdx.x * 256 + threadIdx.x;
  int dv  = tid % 192;
  int rem = tid / 192;
  int pos = rem & 1023;
  int b   = rem >> 10;
  int r = pos >> 5, c = pos & 31;
  const float4* tb = (const float4*)tmp + ((size_t)b * 1024 + c) * 192 + dv;
  float ax = 0.f, ay = 0.f, az = 0.f, aw = 0.f;
#pragma unroll
  for (int dr = -3; dr <= 3; ++dr) {
    int rr = r + dr;
    if (rr >= 0 && rr < 32) {
      float4 v = tb[(size_t)rr * 32 * 192];
      ax += v.x; ay += v.y; az += v.z; aw += v.w;
    }
  }
  float4 xv = ((const float4*)x)[tid];
  float4 wv = ((const float4*)wn)[dv];
  const float inv49 = 1.0f / 49.0f;
  float i0 = 1.0f / sqrtf(1e-7f + ax * inv49);
  float i1 = 1.0f / sqrtf(1e-7f + ay * inv49);
  float i2 = 1.0f / sqrtf(1e-7f + az * inv49);
  float i3 = 1.0f / sqrtf(1e-7f + aw * inv49);
  f16x4 o;
  o[0] = (_Float16)(xv.x * i0 * wv.x);
  o[1] = (_Float16)(xv.y * i1 * wv.y);
  o[2] = (_Float16)(xv.z * i2 * wv.z);
  o[3] = (_Float16)(xv.w * i3 * wv.w);
  *(f16x4*)(xn + (size_t)tid * 4) = o;
}

// ---------- weight conversion f32 -> f16 ----------
__global__ __launch_bounds__(256)
void convw(const float* __restrict__ wq, const float* __restrict__ wk,
           const float* __restrict__ wv, const float* __restrict__ wo,
           ushort_t* __restrict__ bqkv, ushort_t* __restrict__ bwo) {
  int tid = blockIdx.x * 256 + threadIdx.x;   // 589824/4 threads
  float4 a = ((const float4*)wq)[tid];
  float4 b = ((const float4*)wk)[tid];
  float4 c = ((const float4*)wv)[tid];
  float4 d = ((const float4*)wo)[tid];
  f16x4 pa, pb, pc, pd;
  pa[0]=(_Float16)a.x; pa[1]=(_Float16)a.y; pa[2]=(_Float16)a.z; pa[3]=(_Float16)a.w;
  pb[0]=(_Float16)b.x; pb[1]=(_Float16)b.y; pb[2]=(_Float16)b.z; pb[3]=(_Float16)b.w;
  pc[0]=(_Float16)c.x; pc[1]=(_Float16)c.y; pc[2]=(_Float16)c.z; pc[3]=(_Float16)c.w;
  pd[0]=(_Float16)d.x; pd[1]=(_Float16)d.y; pd[2]=(_Float16)d.z; pd[3]=(_Float16)d.w;
  ((f16x4*)bqkv)[tid]             = pa;
  ((f16x4*)(bqkv + 589824))[tid]  = pb;
  ((f16x4*)(bqkv + 1179648))[tid] = pc;
  ((f16x4*)bwo)[tid]              = pd;
}

// ---------- GEMM: out[m][n] = sum_k A[m][k]*B[n][k] (+bias) ----------
// MODE 0: N=2304 -> scatter Q (scaled 0.125*log2e), K, V^T kv-permuted (f16)
// MODE 1: N=768  -> d_out fp32 row-major
template <int MODE>
__global__ __launch_bounds__(256)
void gemm_f16(const ushort_t* __restrict__ A, const ushort_t* __restrict__ B,
              const float* __restrict__ b0, const float* __restrict__ b1,
              const float* __restrict__ b2,
              ushort_t* __restrict__ q, ushort_t* __restrict__ k,
              ushort_t* __restrict__ v, float* __restrict__ outf, int nbn) {
  __shared__ __align__(16) ushort_t As[128 * 32];
  __shared__ __align__(16) ushort_t Bs[128 * 32];

  const int bid = blockIdx.x;
  const int bm = bid / nbn, bn = bid % nbn;
  const int tid = threadIdx.x;
  const int w = tid >> 6, l = tid & 63;
  const int wr = w >> 1, wc = w & 1;
  const int lr = l & 15, lg = l >> 4;

  f32x4 acc[4][4] = {};

  const ushort_t* Ab = A + (size_t)bm * 128 * 768;
  const ushort_t* Bb = B + (size_t)bn * 128 * 768;
  const int srow = w * 32 + (l >> 2);
  const int scol = (l & 3) * 8;

  for (int kt = 0; kt < 24; ++kt) {
    const int k0 = kt * 32;
    gload_lds16(Ab + (size_t)srow * 768 + k0 + scol,        As + (w * 32) * 32);
    gload_lds16(Ab + (size_t)(srow + 16) * 768 + k0 + scol, As + (w * 32 + 16) * 32);
    gload_lds16(Bb + (size_t)srow * 768 + k0 + scol,        Bs + (w * 32) * 32);
    gload_lds16(Bb + (size_t)(srow + 16) * 768 + k0 + scol, Bs + (w * 32 + 16) * 32);
    __syncthreads();
    f16x8 af[4], bf[4];
#pragma unroll
    for (int r = 0; r < 4; ++r)
      af[r] = *(const f16x8*)(As + (wr * 64 + r * 16 + lr) * 32 + lg * 8);
#pragma unroll
    for (int c = 0; c < 4; ++c)
      bf[c] = *(const f16x8*)(Bs + (wc * 64 + c * 16 + lr) * 32 + lg * 8);
#pragma unroll
    for (int r = 0; r < 4; ++r)
#pragma unroll
      for (int c = 0; c < 4; ++c)
        acc[r][c] = __builtin_amdgcn_mfma_f32_16x16x32_f16(af[r], bf[c], acc[r][c], 0, 0, 0);
    __syncthreads();
  }

  // epilogue. C/D layout: col = lane&15, row = (lane>>4)*4 + reg  [m89/m91]
#pragma unroll
  for (int r = 0; r < 4; ++r) {
#pragma unroll
    for (int c = 0; c < 4; ++c) {
      const int n = bn * 128 + wc * 64 + c * 16 + lr;
      const int mbase = bm * 128 + wr * 64 + r * 16 + lg * 4;
      if (MODE == 0) {
        const int region = n / 768;          // uniform per block (768%128==0)
        const int nn = n - region * 768;
        const int hh = nn >> 6, hd = nn & 63;
        const float bb = (region == 0 ? b0 : region == 1 ? b1 : b2)[nn];
        if (region == 2) {
          // V^T with kv-permuted columns: column tile*64+slot holds V[tile*64+sigma(slot)].
          // Here we invert: token s goes to column s' = tile*64 + sigma^{-1}(s&63).
          // s0 is a multiple of 4 -> 4 consecutive s map to 4 consecutive slots.
          const int bi = mbase >> 10, s0 = mbase & 1023;
          const int tile = s0 >> 6, q6 = s0 & 63;
          const int aa = q6 >> 5, r5 = q6 & 31;
          const int t1 = r5 >> 3, h2 = (r5 >> 2) & 1;
          const int g = t1 >> 1, j = (2 * t1) & 3;
          const int s0p = (tile << 6) + (((aa << 1) + g) << 4) + (h2 << 3) + 2 * j;
          f16x4 pv;
#pragma unroll
          for (int gi = 0; gi < 4; ++gi) pv[gi] = (_Float16)(acc[r][c][gi] + bb);
          *(f16x4*)(v + (((size_t)(bi * 12 + hh)) * 64 + hd) * 1024 + s0p) = pv;
        } else {
#pragma unroll
          for (int gi = 0; gi < 4; ++gi) {
            const int m = mbase + gi;
            const int bi = m >> 10, s = m & 1023;
            const float val = acc[r][c][gi] + bb;
            if (region == 0)
              q[(((size_t)(bi * 12 + hh)) * 1024 + s) * 64 + hd] = f2h(val * (0.125f * LOG2E));
            else
              k[(((size_t)(bi * 12 + hh)) * 1024 + s) * 64 + hd] = f2h(val);
          }
        }
      } else {
        const float bb = b0[n];
#pragma unroll
        for (int gi = 0; gi < 4; ++gi) {
          const int m = mbase + gi;
          outf[(size_t)m * 768 + n] = acc[r][c][gi] + bb;
        }
      }
    }
  }
}

// ---------- fused flash attention, 8 waves x 32 q-rows, 32x32 MFMA ----------
// qb: [96][1024][64] f16 (scaled 0.125*log2e), kb: [96][1024][64] f16,
// vt: [96][64][1024] f16 with kv-permuted columns per 64-tile.
// S^T = mfma(K, Q): lane holds P[q=lane&31][kv rows]; softmax fully lane-local
// (one shfl_xor(32) per reduce). O^T = mfma(V^T, P): col=q -> rescale lane-local.
__global__ __launch_bounds__(512)
void attn_fused2(const ushort_t* __restrict__ qb, const ushort_t* __restrict__ kb,
                 const ushort_t* __restrict__ vt, ushort_t* __restrict__ ao) {
  __shared__ __align__(16) ushort_t smem[16384];   // 32 KB: K dbuf 16K + V dbuf 16K
  const int tid = threadIdx.x;
  const int w = tid >> 6, l = tid & 63;
  const int lq = l & 31, hi = l >> 5;

  // XCD-contiguous remap: 48 consecutive cids per XCD; 4 blocks/head stay together
  const int bid = blockIdx.x;
  const int cid = (bid & 7) * 48 + (bid >> 3);
  const int bh = cid >> 2, qt = cid & 3;
  const int b = bh / 12, h = bh % 12;

  const ushort_t* qp = qb + ((size_t)bh * 1024 + qt * 256 + w * 32) * 64;
  const ushort_t* kp = kb + (size_t)bh * 65536;
  const ushort_t* vp = vt + (size_t)bh * 65536;

  // Q B-frags: lane holds col q = lq, k = hi*8+i within each 16-chunk
  f16x8 qf[4];
#pragma unroll
  for (int kc = 0; kc < 4; ++kc)
    qf[kc] = *(const f16x8*)(qp + lq * 64 + kc * 16 + hi * 8);

  // staging geometry: chunk tid of 512 covers one 8KB tile; pre-swizzled source col
  const int srow = tid >> 3;                    // 0..63 (kv row for K, d row for V^T)
  const int scol = (tid & 7) ^ (srow & 7);      // XOR swizzle, inverse == forward

  f32x16 oacc0 = {}, oacc1 = {};
  float mrun = -1e30f, lrun = 0.f;

  // prologue: stage tile 0 into buf 0
  {
    gload_lds16(kp + (size_t)srow * 64 + scol * 8,
                (char*)smem + w * 1024);
    gload_lds16(vp + (size_t)srow * 1024 + scol * 8,
                (char*)smem + 16384 + w * 1024);
  }
  __syncthreads();

  int buf = 0;
  for (int t = 0; t < 16; ++t) {
    if (t < 15) {
      const int kv0 = (t + 1) << 6;
      gload_lds16(kp + (size_t)(kv0 + srow) * 64 + scol * 8,
                  (char*)smem + (buf ^ 1) * 8192 + w * 1024);
      gload_lds16(vp + (size_t)srow * 1024 + kv0 + scol * 8,
                  (char*)smem + 16384 + (buf ^ 1) * 8192 + w * 1024);
    }
    const char* kbase = (const char*)smem + buf * 8192;
    const char* vbase = (const char*)smem + 16384 + buf * 8192;
    const int cswz = (lq & 7);

    f16x8 ka0[4], ka1[4];
#pragma unroll
    for (int kc = 0; kc < 4; ++kc) {
      ka0[kc] = *(const f16x8*)(kbase + lq * 128 + (((kc * 2 + hi) ^ cswz) * 16));
      ka1[kc] = *(const f16x8*)(kbase + (32 + lq) * 128 + (((kc * 2 + hi) ^ cswz) * 16));
    }
    f32x16 s0 = {}, s1 = {};
    __builtin_amdgcn_s_setprio(1);
#pragma unroll
    for (int kc = 0; kc < 4; ++kc) {
      s0 = __builtin_amdgcn_mfma_f32_32x32x16_f16(ka0[kc], qf[kc], s0, 0, 0, 0);
      s1 = __builtin_amdgcn_mfma_f32_32x32x16_f16(ka1[kc], qf[kc], s1, 0, 0, 0);
    }
    __builtin_amdgcn_s_setprio(0);

    // ---- online softmax, lane-local (q = lq on both hi-halves) ----
    float mt = -1e30f;
#pragma unroll
    for (int r = 0; r < 16; ++r) { mt = fmaxf(mt, s0[r]); mt = fmaxf(mt, s1[r]); }
    mt = fmaxf(mt, __shfl_xor(mt, 32, 64));
    const float mnew = fmaxf(mrun, mt);
    const float corr = __builtin_exp2f(mrun - mnew);
    float sum = 0.f;
#pragma unroll
    for (int r = 0; r < 16; ++r) {
      s0[r] = __builtin_exp2f(s0[r] - mnew); sum += s0[r];
      s1[r] = __builtin_exp2f(s1[r] - mnew); sum += s1[r];
    }
    sum += __shfl_xor(sum, 32, 64);
    lrun = lrun * corr + sum;
    mrun = mnew;
#pragma unroll
    for (int r = 0; r < 16; ++r) { oacc0[r] *= corr; oacc1[r] *= corr; }

    // ---- pack P pairs; V's kv-permutation makes these direct B-frags ----
    uint_t pk0[8], pk1[8];
#pragma unroll
    for (int tt = 0; tt < 8; ++tt) {
      pk0[tt] = packpair(s0[2 * tt], s0[2 * tt + 1]);
      pk1[tt] = packpair(s1[2 * tt], s1[2 * tt + 1]);
    }
    f16x8 pb0 = mk8(pk0[0], pk0[1], pk0[2], pk0[3]);
    f16x8 pb1 = mk8(pk0[4], pk0[5], pk0[6], pk0[7]);
    f16x8 pb2 = mk8(pk1[0], pk1[1], pk1[2], pk1[3]);
    f16x8 pb3 = mk8(pk1[4], pk1[5], pk1[6], pk1[7]);

    f16x8 va0[4], va1[4];
#pragma unroll
    for (int c = 0; c < 4; ++c) {
      va0[c] = *(const f16x8*)(vbase + lq * 128 + (((c * 2 + hi) ^ cswz) * 16));
      va1[c] = *(const f16x8*)(vbase + (32 + lq) * 128 + (((c * 2 + hi) ^ cswz) * 16));
    }
    __builtin_amdgcn_s_setprio(1);
    oacc0 = __builtin_amdgcn_mfma_f32_32x32x16_f16(va0[0], pb0, oacc0, 0, 0, 0);
    oacc1 = __builtin_amdgcn_mfma_f32_32x32x16_f16(va1[0], pb0, oacc1, 0, 0, 0);
    oacc0 = __builtin_amdgcn_mfma_f32_32x32x16_f16(va0[1], pb1, oacc0, 0, 0, 0);
    oacc1 = __builtin_amdgcn_mfma_f32_32x32x16_f16(va1[1], pb1, oacc1, 0, 0, 0);
    oacc0 = __builtin_amdgcn_mfma_f32_32x32x16_f16(va0[2], pb2, oacc0, 0, 0, 0);
    oacc1 = __builtin_amdgcn_mfma_f32_32x32x16_f16(va1[2], pb2, oacc1, 0, 0, 0);
    oacc0 = __builtin_amdgcn_mfma_f32_32x32x16_f16(va0[3], pb3, oacc0, 0, 0, 0);
    oacc1 = __builtin_amdgcn_mfma_f32_32x32x16_f16(va1[3], pb3, oacc1, 0, 0, 0);
    __builtin_amdgcn_s_setprio(0);

    __syncthreads();    // drains vmcnt (stage) + lgkm; protects buf swap
    buf ^= 1;
  }

  // ---- epilogue: O^T -> swizzled LDS -> coalesced global f16 rows ----
  const float invl = 1.0f / lrun;
  uint_t* ot = (uint_t*)smem + w * 1024 + lq * 32;   // wave-private 4KB tile
#pragma unroll
  for (int tt = 0; tt < 8; ++tt) {
    // d-pair base (dword col): rows crow(2t),crow(2t+1) = pb(t)+4hi (+32 for oacc1)
    const int base = (tt & 1) + ((tt >> 1) << 2) + 2 * hi;
    ot[base ^ lq]        = packpair(oacc0[2 * tt] * invl, oacc0[2 * tt + 1] * invl);
    ot[(base + 16) ^ lq] = packpair(oacc1[2 * tt] * invl, oacc1[2 * tt + 1] * invl);
  }
  __syncthreads();
  const int row = tid >> 1, halfc = tid & 1;
  const int w2 = row >> 5, qq = row & 31;
  const uint_t* srcp = (const uint_t*)smem + w2 * 1024 + qq * 32;
  ushort_t* dst = ao + (size_t)(b * 1024 + qt * 256 + row) * 768 + h * 64 + halfc * 32;
#pragma unroll
  for (int jj = 0; jj < 4; ++jj) {
    u32x4 tv;
#pragma unroll
    for (int i2 = 0; i2 < 4; ++i2)
      tv[i2] = srcp[(halfc * 16 + jj * 4 + i2) ^ qq];
    *(u32x4*)(dst + jj * 8) = tv;
  }
}

// ---------- launch ----------
extern "C" void kernel_launch(void* const* d_in, const int* in_sizes, int n_in,
                              void* d_out, int out_size, void* d_ws, size_t ws_size,
                              hipStream_t stream) {
  const float* x  = (const float*)d_in[0];
  const float* nw = (const float*)d_in[1];
  const float* wq = (const float*)d_in[2];
  const float* bq = (const float*)d_in[3];
  const float* wk = (const float*)d_in[4];
  const float* bk = (const float*)d_in[5];
  const float* wv = (const float*)d_in[6];
  const float* bv = (const float*)d_in[7];
  const float* wo = (const float*)d_in[8];
  const float* bo = (const float*)d_in[9];
  float* out = (float*)d_out;

  char* ws = (char*)d_ws;
  float*    tmp   = (float*)ws;                   // consumed by lrn_b, then reused
  ushort_t* qbuf  = (ushort_t*)(ws);
  ushort_t* kbuf  = (ushort_t*)(ws + 12582912);
  ushort_t* xn    = (ushort_t*)(ws + 25165824);   // 12,582,912
  ushort_t* bwqkv = (ushort_t*)(ws + 37748736);   //  3,538,944
  ushort_t* bwo   = (ushort_t*)(ws + 41287680);   //  1,179,648
  ushort_t* vtb   = (ushort_t*)(ws + 42467328);   // 12,582,912
  ushort_t* aout  = (ushort_t*)(ws + 55050240);   // 12,582,912  (total 67,633,152)

  lrn_a<<<6144, 256, 0, stream>>>(x, tmp);
  lrn_b<<<6144, 256, 0, stream>>>(x, tmp, nw, xn);
  convw<<<576, 256, 0, stream>>>(wq, wk, wv, wo, bwqkv, bwo);
  gemm_f16<0><<<64 * 18, 256, 0, stream>>>(xn, bwqkv, bq, bk, bv,
                                           qbuf, kbuf, vtb, nullptr, 18);
  attn_fused2<<<384, 512, 0, stream>>>(qbuf, kbuf, vtb, aout);
  gemm_f16<1><<<64 * 6, 256, 0, stream>>>(aout, bwo, bo, nullptr, nullptr, nullptr,
                                          nullptr, nullptr, out, 6);
}